// Round 18
// baseline (229.168 us; speedup 1.0000x reference)
//
#include <hip/hip_runtime.h>
#include <stdint.h>

#define NB 32      // batch
#define NC 32      // in channels
#define NN 1024    // nodes
#define NT 12      // time
#define NJ (NB*NC*NT)  // 12288
#define NO 32      // out channels
#define TIN 224    // (2*3+1)*32
#define HBE ((size_t)NJ*NN)   // elements per [j][n] buffer

typedef __attribute__((ext_vector_type(8))) __bf16 bf16x8;
typedef __attribute__((ext_vector_type(4))) float f32x4;
typedef unsigned short u16;
typedef unsigned int u32;

__device__ __forceinline__ u16 f2bf(float f){
  u32 u = __float_as_uint(f);
  u32 r = (u + 0x7FFFu + ((u >> 16) & 1u)) >> 16;   // RNE
  return (u16)r;
}
__device__ __forceinline__ float bf2f(u16 h){
  return __uint_as_float(((u32)h) << 16);
}
__device__ __forceinline__ float bflo(u32 v){ return __uint_as_float(v << 16); }
__device__ __forceinline__ float bfhi(u32 v){ return __uint_as_float(v & 0xFFFF0000u); }

typedef const __attribute__((address_space(1))) u32* gp_t;
typedef __attribute__((address_space(3))) u32* lp_t;
__device__ __forceinline__ void gll16(const void* g, void* l){
  __builtin_amdgcn_global_load_lds((gp_t)g, (lp_t)l, 16, 0, 0);
}

// ---------- prep adj: At[z][m][n] = bf16(adj_z[n][m]) ; Ar[z][n][m] = bf16(adj_z[n][m]) ----------
__global__ __launch_bounds__(256) void k_prep_adj(const float* __restrict__ a0,
      const float* __restrict__ a1, const float* __restrict__ a2,
      u16* __restrict__ At, u16* __restrict__ Ar){
  __shared__ float tile[32][33];
  const float* A = (blockIdx.z==0) ? a0 : (blockIdx.z==1 ? a1 : a2);
  int n0 = blockIdx.x*32, m0 = blockIdx.y*32;
  int tx = threadIdx.x, ty = threadIdx.y;  // block (32,8)
  u16* dstR = Ar + (size_t)blockIdx.z*NN*NN;
  #pragma unroll
  for (int r=0;r<4;r++){
    float v = A[(size_t)(n0 + ty + 8*r)*NN + m0 + tx];
    tile[ty + 8*r][tx] = v;
    dstR[(size_t)(n0 + ty + 8*r)*NN + m0 + tx] = f2bf(v);
  }
  __syncthreads();
  u16* dst = At + (size_t)blockIdx.z*NN*NN;
  #pragma unroll
  for (int r=0;r<4;r++)
    dst[(size_t)(m0 + ty + 8*r)*NN + n0 + tx] = f2bf(tile[tx][ty + 8*r]);
}

// ---------- prep x (fallback layout): Zt[j][n] = bf16(x[p,n,t]) ----------
__global__ __launch_bounds__(256) void k_prep_x2(const float* __restrict__ x, u16* __restrict__ Zt){
  __shared__ float tl[64][13];
  int p = blockIdx.y, n0 = blockIdx.x*64;
  const float* xp = x + (size_t)p*NN*NT + (size_t)n0*NT;
  int tid = threadIdx.x;
  #pragma unroll
  for (int k=0;k<3;k++){
    int e = tid + k*256;
    float v = xp[e];
    tl[e/12][e%12] = v;
  }
  __syncthreads();
  #pragma unroll
  for (int k=0;k<3;k++){
    int e = tid + k*256;
    int t = e >> 6, nn = e & 63;
    Zt[((size_t)p*NT + t)*NN + n0 + nn] = f2bf(tl[nn][t]);
  }
}

// ---------- FUSED: bgemm0 (At2 = (A^2)^T, blocks 0..191) + pmix2 (blocks 192..703) ----------
// Independent halves co-scheduled in one dispatch. NOTE: Ar must NOT alias any
// buffer written by the pmix2 half (R17 bug: Ar==Base raced) — Ar now has its
// own slot. LDS union 64 KB -> 2 blocks/CU.
__global__ __launch_bounds__(256) void k_fusemix(
    const u16* __restrict__ At, const u16* __restrict__ Ar, u16* __restrict__ At2,
    const float* __restrict__ x, const float* __restrict__ W,
    const float* __restrict__ bias, u16* __restrict__ U, u16* __restrict__ Base){
  __shared__ __align__(16) u16 smem[32768];   // 64 KB union
  int id = blockIdx.x;
  int tid = threadIdx.x;

  if (id < 192){
    // ---- bgemm0 body (R8-proven 2-phase dbuf, MODE 0) ----
    int w = tid >> 6, lane = tid & 63;
    int bx = id & 7, by = (id >> 3) & 7, z = id >> 6;
    int m0 = by*128, j0 = bx*128;
    int wr = w >> 1, wc = w & 1;
    int lrow = lane & 15, kgrp = lane >> 4;
    int lr8 = lane >> 3, lc8 = lane & 7;

    const u16* Amat = Ar + (size_t)z*NN*NN;
    const u16* Bmat = At + (size_t)z*NN*NN;
    u16* Out = At2 + (size_t)z*NN*NN;

    f32x4 acc[4][4];
    #pragma unroll
    for (int i=0;i<4;i++)
      #pragma unroll
      for (int jj=0;jj<4;jj++)
        acc[i][jj] = (f32x4){0.f,0.f,0.f,0.f};

    const u16* Abase = Amat + (size_t)m0*1024;
    const u16* Bbase = Bmat + (size_t)j0*1024;

    auto stage = [&](int kt, int d){
      int k0 = kt*64;
      u16* As = smem + d*8192;
      u16* Bs = smem + 16384 + d*8192;
      #pragma unroll
      for (int i=0;i<4;i++){
        int q = w*4 + i;
        int row = q*8 + lr8;
        gll16(Abase + (size_t)row*1024 + k0 + lc8*8, As + q*512);
        gll16(Bbase + (size_t)row*1024 + k0 + lc8*8, Bs + q*512);
      }
    };
    auto compute = [&](int d){
      const u16* As = smem + d*8192;
      const u16* Bs = smem + 16384 + d*8192;
      #pragma unroll
      for (int kk=0; kk<2; ++kk){
        bf16x8 af[4], bfr[4];
        #pragma unroll
        for (int mi=0;mi<4;mi++)
          af[mi] = *reinterpret_cast<const bf16x8*>(&As[(wr*64+mi*16+lrow)*64 + kk*32 + kgrp*8]);
        #pragma unroll
        for (int ji=0;ji<4;ji++)
          bfr[ji] = *reinterpret_cast<const bf16x8*>(&Bs[(wc*64+ji*16+lrow)*64 + kk*32 + kgrp*8]);
        #pragma unroll
        for (int mi=0;mi<4;mi++)
          #pragma unroll
          for (int ji=0;ji<4;ji++)
            acc[mi][ji] = __builtin_amdgcn_mfma_f32_16x16x32_bf16(af[mi], bfr[ji], acc[mi][ji], 0, 0, 0);
      }
    };

    stage(0, 0);
    #pragma unroll 1
    for (int kt2=0; kt2<8; ++kt2){
      stage(2*kt2+1, 1);
      asm volatile("s_waitcnt vmcnt(8)" ::: "memory");
      __builtin_amdgcn_s_barrier();
      compute(0);
      __builtin_amdgcn_s_barrier();
      if (kt2 < 7){
        stage(2*kt2+2, 0);
        asm volatile("s_waitcnt vmcnt(8)" ::: "memory");
      } else {
        asm volatile("s_waitcnt vmcnt(0)" ::: "memory");
      }
      __builtin_amdgcn_s_barrier();
      compute(1);
      __builtin_amdgcn_s_barrier();
    }

    #pragma unroll
    for (int mi=0;mi<4;mi++){
      #pragma unroll
      for (int ji=0;ji<4;ji++){
        int jg = j0 + wc*64 + ji*16 + lrow;
        int mg = m0 + wr*64 + mi*16 + kgrp*4;
        ushort4 st;
        st.x = f2bf(acc[mi][ji][0]);
        st.y = f2bf(acc[mi][ji][1]);
        st.z = f2bf(acc[mi][ji][2]);
        st.w = f2bf(acc[mi][ji][3]);
        *reinterpret_cast<ushort4*>(&Out[(size_t)jg*NN + mg]) = st;
      }
    }
  } else {
    // ---- pmix2 body (R16-proven): fused prep_x + MFMA premix ----
    int pid = id - 192;
    int n0 = (pid & 15)*64, b = pid >> 4;
    u16* X = smem;                       // [t][nl][c pitch 40] = 60 KB

    #pragma unroll
    for (int k=0;k<24;k++){
      int idx = tid + k*256;            // 6144 float4 per block
      int c = idx / 192, f = idx - c*192;
      float4 v = *reinterpret_cast<const float4*>(
          x + ((size_t)(b*NC + c)*NN + n0)*NT + f*4);
      #pragma unroll
      for (int j=0;j<4;j++){
        int e = f*4 + j;
        int nl = e / 12, tt = e - nl*12;
        float fv = (j==0)?v.x:(j==1)?v.y:(j==2)?v.z:v.w;
        X[(tt*64 + nl)*40 + c] = f2bf(fv);
      }
    }

    int lane = tid & 63, w = tid >> 6;
    int lrow = lane & 15, kgrp = lane >> 4;

    bf16x8 af[7][2];
    #pragma unroll
    for (int g=0; g<7; g++){
      #pragma unroll
      for (int ot=0; ot<2; ot++){
        const float* wr = W + (size_t)(ot*16 + lrow)*TIN + g*32 + kgrp*8;
        float4 wa = *reinterpret_cast<const float4*>(wr);
        float4 wb = *reinterpret_cast<const float4*>(wr + 4);
        u32 tmp[4];
        tmp[0] = (u32)f2bf(wa.x) | ((u32)f2bf(wa.y) << 16);
        tmp[1] = (u32)f2bf(wa.z) | ((u32)f2bf(wa.w) << 16);
        tmp[2] = (u32)f2bf(wb.x) | ((u32)f2bf(wb.y) << 16);
        tmp[3] = (u32)f2bf(wb.z) | ((u32)f2bf(wb.w) << 16);
        af[g][ot] = *reinterpret_cast<bf16x8*>(tmp);
      }
    }
    float4 bias4[2];
    #pragma unroll
    for (int ot=0; ot<2; ot++)
      bias4[ot] = *reinterpret_cast<const float4*>(bias + ot*16 + kgrp*4);

    __syncthreads();

    #pragma unroll 1
    for (int t=0; t<12; ++t){
      bf16x8 bfr = *reinterpret_cast<const bf16x8*>(
          &X[((t*64) + w*16 + lrow)*40 + kgrp*8]);
      #pragma unroll
      for (int g=0; g<7; g++){
        u16* dstb = (g==0) ? Base : (U + (size_t)(g-1)*HBE);
        #pragma unroll
        for (int ot=0; ot<2; ot++){
          f32x4 acc = (f32x4){0.f,0.f,0.f,0.f};
          acc = __builtin_amdgcn_mfma_f32_16x16x32_bf16(af[g][ot], bfr, acc, 0, 0, 0);
          if (g==0){
            acc[0] += bias4[ot].x; acc[1] += bias4[ot].y;
            acc[2] += bias4[ot].z; acc[3] += bias4[ot].w;
          }
          int o = ot*16 + kgrp*4;
          size_t rb = ((size_t)(b*NO + o)*NT + t)*NN + n0 + w*16 + lrow;
          dstb[rb]                    = f2bf(acc[0]);
          dstb[rb + (size_t)NT*NN]    = f2bf(acc[1]);
          dstb[rb + (size_t)2*NT*NN]  = f2bf(acc[2]);
          dstb[rb + (size_t)3*NT*NN]  = f2bf(acc[3]);
        }
      }
    }
  }
}

// ---------- batched GEMM, 2-phase double-buffered (fallback path), MODE 2/3 ----------
#define BKK 64
template<int MODE>
__global__ __launch_bounds__(256) void k_bgemm(
    const u16* __restrict__ At, const u16* __restrict__ Ar,
    u16* __restrict__ At2, const u16* __restrict__ Zt,
    u16* __restrict__ Db){
  __shared__ __align__(16) u16 As[2][128*BKK];
  __shared__ __align__(16) u16 Bs[2][128*BKK];
  int tid = threadIdx.x;
  int w = tid >> 6, lane = tid & 63;
  int z = blockIdx.z;
  int m0 = blockIdx.y * 128, j0 = blockIdx.x * 128;
  int wr = w >> 1, wc = w & 1;
  int lrow = lane & 15, kgrp = lane >> 4;
  int lr8 = lane >> 3, lc8 = lane & 7;

  const u16* Amat; const u16* Bmat; u16* Out;
  if (MODE==0){
    Amat = Ar + (size_t)z*NN*NN; Bmat = At + (size_t)z*NN*NN; Out = At2 + (size_t)z*NN*NN;
  } else if (MODE==2){
    Amat = At + (size_t)z*NN*NN; Bmat = Zt; Out = Db + (size_t)(2*z)*HBE;
  } else {
    Amat = At + (size_t)z*NN*NN; Bmat = Db + (size_t)(2*z)*HBE; Out = Db + (size_t)(2*z+1)*HBE;
  }

  f32x4 acc[4][4];
  #pragma unroll
  for (int i=0;i<4;i++)
    #pragma unroll
    for (int jj=0;jj<4;jj++)
      acc[i][jj] = (f32x4){0.f,0.f,0.f,0.f};

  const u16* Abase = Amat + (size_t)m0*1024;
  const u16* Bbase = Bmat + (size_t)j0*1024;

  auto stage = [&](int kt, int d){
    int k0 = kt*BKK;
    #pragma unroll
    for (int i=0;i<4;i++){
      int q = w*4 + i;
      int row = q*8 + lr8;
      gll16(Abase + (size_t)row*1024 + k0 + lc8*8, (u16*)&As[d][0] + q*512);
      gll16(Bbase + (size_t)row*1024 + k0 + lc8*8, (u16*)&Bs[d][0] + q*512);
    }
  };
  auto compute = [&](int d){
    #pragma unroll
    for (int kk=0; kk<2; ++kk){
      bf16x8 af[4], bfr[4];
      #pragma unroll
      for (int mi=0;mi<4;mi++)
        af[mi] = *reinterpret_cast<const bf16x8*>(&As[d][(wr*64+mi*16+lrow)*BKK + kk*32 + kgrp*8]);
      #pragma unroll
      for (int ji=0;ji<4;ji++)
        bfr[ji] = *reinterpret_cast<const bf16x8*>(&Bs[d][(wc*64+ji*16+lrow)*BKK + kk*32 + kgrp*8]);
      #pragma unroll
      for (int mi=0;mi<4;mi++)
        #pragma unroll
        for (int ji=0;ji<4;ji++)
          acc[mi][ji] = __builtin_amdgcn_mfma_f32_16x16x32_bf16(af[mi], bfr[ji], acc[mi][ji], 0, 0, 0);
    }
  };

  stage(0, 0);
  #pragma unroll 1
  for (int kt2=0; kt2<8; ++kt2){
    stage(2*kt2+1, 1);
    asm volatile("s_waitcnt vmcnt(8)" ::: "memory");
    __builtin_amdgcn_s_barrier();
    compute(0);
    __builtin_amdgcn_s_barrier();
    if (kt2 < 7){
      stage(2*kt2+2, 0);
      asm volatile("s_waitcnt vmcnt(8)" ::: "memory");
    } else {
      asm volatile("s_waitcnt vmcnt(0)" ::: "memory");
    }
    __builtin_amdgcn_s_barrier();
    compute(1);
    __builtin_amdgcn_s_barrier();
  }

  #pragma unroll
  for (int mi=0;mi<4;mi++){
    #pragma unroll
    for (int ji=0;ji<4;ji++){
      int jg = j0 + wc*64 + ji*16 + lrow;
      int mg = m0 + wr*64 + mi*16 + kgrp*4;
      ushort4 st;
      st.x = f2bf(acc[mi][ji][0]);
      st.y = f2bf(acc[mi][ji][1]);
      st.z = f2bf(acc[mi][ji][2]);
      st.w = f2bf(acc[mi][ji][3]);
      *reinterpret_cast<ushort4*>(&Out[(size_t)jg*NN + mg]) = st;
    }
  }
}

// ---------- fused 6-term GEMM (R11-proven main loop) + fused f32 transpose epilogue ----------
__global__ __launch_bounds__(512) void k_gemm6p(
    const u16* __restrict__ At, const u16* __restrict__ At2,
    const u16* __restrict__ U, const u16* __restrict__ Base,
    float* __restrict__ y){
  __shared__ __align__(16) u16 lds[2][28672];   // per buf: A 256x64 @0, B 192x64 @16384
  const int tid = threadIdx.x;
  const int w = tid >> 6, lane = tid & 63;
  const int lrow = lane & 15, kgrp = lane >> 4;
  const int wm = w & 3, wj = w >> 2;
  const int swz = (lrow & 7) << 3;           // read-side XOR (u16 units, 16B slots)

  const int orig = blockIdx.x;
  const int wg = (orig & 7)*32 + (orig >> 3);  // bijective XCD remap (256 = 8*32)
  const int m0 = (wg >> 6) * 256;
  const int j0 = (wg & 63) * 192;

  const int srow = lane >> 3;
  const int skoff = ((lane & 7) << 3) ^ ((srow & 7) << 3);   // inverse-swizzled k-off
  size_t rowoff[7]; int ldsoff[7]; bool isA[7];
  #pragma unroll
  for (int i=0;i<7;i++){
    int c = w*7 + i;
    if (c < 32){
      int row = c*8 + srow;
      isA[i] = true;  rowoff[i] = (size_t)(m0 + row)*1024 + skoff;  ldsoff[i] = c*512;
    } else {
      int cb = c - 32;
      int row = cb*8 + srow;
      isA[i] = false; rowoff[i] = (size_t)(j0 + row)*1024 + skoff;  ldsoff[i] = 16384 + cb*512;
    }
  }

  #define STAGE(t, i) {                                                        \
    int s_ = (t) >> 4;                                                         \
    int k0_ = ((t) & 15) << 6;                                                 \
    const u16* Ab_ = ((s_ & 1) ? At2 : At) + (size_t)(s_ >> 1)*NN*NN;          \
    const u16* src_ = (isA[i] ? Ab_ : (U + (size_t)s_*HBE)) + rowoff[i] + k0_; \
    gll16(src_, &lds[(t) & 1][ldsoff[i]]); }

  f32x4 acc[4][6];
  #pragma unroll
  for (int mi=0;mi<4;mi++)
    #pragma unroll
    for (int ji=0;ji<6;ji++)
      acc[mi][ji] = (f32x4){0.f,0.f,0.f,0.f};

  #pragma unroll
  for (int i=0;i<7;i++) STAGE(0, i)

  #pragma unroll 1
  for (int t=0; t<96; ++t){
    const int d = t & 1;
    if (t < 95){
      STAGE(t+1, 0) STAGE(t+1, 1)
      asm volatile("s_waitcnt vmcnt(2)" ::: "memory");
    } else {
      asm volatile("s_waitcnt vmcnt(0)" ::: "memory");
    }
    __builtin_amdgcn_s_barrier();
    __builtin_amdgcn_sched_barrier(0);

    bf16x8 bf[6][2];
    #pragma unroll
    for (int p=0;p<4;p++){
      if (t < 95){
        if (p==0){ STAGE(t+1, 2) STAGE(t+1, 3) }
        else if (p==1){ STAGE(t+1, 4) STAGE(t+1, 5) }
        else if (p==2){ STAGE(t+1, 6) }
      }
      if (p==0){
        #pragma unroll
        for (int ji=0;ji<6;ji++){
          int row = wj*96 + ji*16 + lrow;
          #pragma unroll
          for (int kk=0;kk<2;kk++)
            bf[ji][kk] = *reinterpret_cast<const bf16x8*>(
              &lds[d][16384 + row*64 + ((kk*32 + kgrp*8) ^ swz)]);
        }
      }
      bf16x8 af0, af1;
      {
        int row = wm*64 + p*16 + lrow;
        af0 = *reinterpret_cast<const bf16x8*>(&lds[d][row*64 + ((kgrp*8) ^ swz)]);
        af1 = *reinterpret_cast<const bf16x8*>(&lds[d][row*64 + ((32 + kgrp*8) ^ swz)]);
      }
      __builtin_amdgcn_s_setprio(1);
      #pragma unroll
      for (int ji=0;ji<6;ji++){
        acc[p][ji] = __builtin_amdgcn_mfma_f32_16x16x32_bf16(af0, bf[ji][0], acc[p][ji], 0, 0, 0);
        acc[p][ji] = __builtin_amdgcn_mfma_f32_16x16x32_bf16(af1, bf[ji][1], acc[p][ji], 0, 0, 0);
      }
      __builtin_amdgcn_s_setprio(0);
    }
    __builtin_amdgcn_s_barrier();   // all waves done reading buf d before t+2 stages hit it
  }
  #undef STAGE

  // ---- fused transpose epilogue: y[bo][n][t] f32, via LDS, fully coalesced ----
  float* ldsf = (float*)&lds[0][0];           // 96 KB of the 112 KB staging LDS
  const int bo0 = j0 / NT;                    // j0 % 12 == 0
  #pragma unroll 1
  for (int r=0; r<2; ++r){
    if (r) __syncthreads();                   // round-0 readers done before round-1 writers
    if (wj == r){
      #pragma unroll
      for (int ji=0;ji<6;ji++){
        int jl = ji*16 + lrow;                // 0..95 within this wj half
        int bo8 = jl / NT, tt = jl - bo8*NT;  // bo8 in 0..7
        int jg = j0 + r*96 + jl;
        #pragma unroll
        for (int mi=0;mi<4;mi++){
          int nl = wm*64 + mi*16 + kgrp*4;
          const ushort4 bv = *reinterpret_cast<const ushort4*>(&Base[(size_t)jg*NN + m0 + nl]);
          float* p = ldsf + bo8*3072 + nl*NT + tt;
          p[0]  = acc[mi][ji][0] + bf2f(bv.x);
          p[12] = acc[mi][ji][1] + bf2f(bv.y);
          p[24] = acc[mi][ji][2] + bf2f(bv.z);
          p[36] = acc[mi][ji][3] + bf2f(bv.w);
        }
      }
    }
    __syncthreads();                          // writers done before readers
    #pragma unroll
    for (int q=0;q<12;q++){
      int idx = tid + q*512;                  // 6144 float4 per round
      int bo8 = idx / 768, off = (idx - bo8*768)*4;
      *reinterpret_cast<float4*>(y + ((size_t)(bo0 + r*8 + bo8))*(NN*NT) + (size_t)m0*NT + off)
        = *reinterpret_cast<const float4*>(ldsf + bo8*3072 + off);
    }
  }
}

// ---------- final channel mix (fallback path only) ----------
__global__ __launch_bounds__(256) void k_mix7(u16* zt_y,
    const u16* __restrict__ Db, const float* __restrict__ W,
    const float* __restrict__ bias){
  __shared__ u32 X[112][64];   // 28 KB
  int tid = threadIdx.x;
  int n0 = blockIdx.x*128;
  int bt = blockIdx.y;
  int b = bt / NT, t = bt - b*NT;
  int lane = tid & 63;
  int og = __builtin_amdgcn_readfirstlane(tid >> 6);

  float a0[8], a1[8];
  #pragma unroll
  for (int oo=0;oo<8;oo++){ float bv = bias[og*8+oo]; a0[oo]=bv; a1[oo]=bv; }

  #pragma unroll 1
  for (int chunk=0; chunk<2; ++chunk){
    if (chunk) __syncthreads();
    #pragma unroll
    for (int k=0;k<28;k++){
      int i = tid + k*256;
      int rl = i >> 6, col = i & 63;
      int r = chunk*112 + rl;
      int s = r >> 5, c = r & 31;
      const u16* src = (s==0) ? zt_y : (Db + (size_t)(s-1)*HBE);
      X[rl][col] = *reinterpret_cast<const u32*>(src + ((size_t)(b*NC + c)*NT + t)*NN + n0 + 2*col);
    }
    __syncthreads();
    #pragma unroll
    for (int cc=0; cc<112; ++cc){
      u32 xp = X[cc][lane];
      float xl = bflo(xp), xh = bfhi(xp);
      #pragma unroll
      for (int oo=0;oo<8;oo++){
        float w = W[(size_t)(og*8+oo)*TIN + chunk*112 + cc];
        a0[oo] += w*xl; a1[oo] += w*xh;
      }
    }
  }

  #pragma unroll
  for (int oo=0;oo<8;oo++){
    u32 pk = (u32)f2bf(a0[oo]) | ((u32)f2bf(a1[oo]) << 16);
    *reinterpret_cast<u32*>(zt_y + ((size_t)(b*NO + og*8+oo)*NT + t)*NN + n0 + 2*lane) = pk;
  }
}

// ---------- final transpose (fallback path) ----------
__global__ __launch_bounds__(256) void k_out2(const u16* __restrict__ Yb,
                                              float* __restrict__ y){
  __shared__ float tl[256][13];
  int n0 = blockIdx.x*256;
  int bo = blockIdx.y;
  int tid = threadIdx.x;
  #pragma unroll
  for (int k=0;k<12;k++)
    tl[tid][k] = bf2f(Yb[((size_t)bo*NT + k)*NN + n0 + tid]);
  __syncthreads();
  float* yp = y + ((size_t)bo*NN + n0)*NT;
  #pragma unroll
  for (int k=0;k<12;k++){
    int i = k*256 + tid;
    yp[i] = tl[i/12][i%12];
  }
}

extern "C" void kernel_launch(void* const* d_in, const int* in_sizes, int n_in,
                              void* d_out, int out_size, void* d_ws, size_t ws_size,
                              hipStream_t stream){
  const float* x    = (const float*)d_in[0];
  const float* a0   = (const float*)d_in[1];
  const float* a1   = (const float*)d_in[2];
  const float* a2   = (const float*)d_in[3];
  const float* W    = (const float*)d_in[4];
  const float* bias = (const float*)d_in[5];
  float* y = (float*)d_out;
  (void)in_sizes; (void)n_in; (void)out_size;

  const size_t atB = (size_t)3*NN*NN*2;     // 6.29 MB
  const size_t ztB = HBE*2;                 // 25.17 MB
  const size_t need_fused = 2*atB + 8*ztB;  // 213.9 MB (R9-R16 verified available)

  if (ws_size >= need_fused){
    char* ws = (char*)d_ws;
    u16* At   = (u16*)ws;  ws += atB;
    u16* At2  = (u16*)ws;  ws += atB;
    u16* Ar   = (u16*)ws;  ws += ztB;        // own slot (former Zc) — NO aliasing with
                                             // pmix2 outputs (R17 race fix)
    u16* U    = (u16*)ws;  ws += 6*ztB;
    u16* Base = (u16*)ws;  ws += ztB;

    k_prep_adj<<<dim3(32,32,3), dim3(32,8), 0, stream>>>(a0, a1, a2, At, Ar);
    k_fusemix<<<704, 256, 0, stream>>>(At, Ar, At2, x, W, bias, U, Base);
    k_gemm6p<<<256, 512, 0, stream>>>(At, At2, U, Base, y);         // writes y directly
  } else {
    // fallback: two dependent batched GEMM dispatches + late mix
    char* ws = (char*)d_ws;
    u16* At  = (u16*)ws;  ws += atB;
    u16* Zt  = (u16*)ws;  ws += ztB;
    u16* Db  = (u16*)ws;  ws += 6*ztB;
    u16* Ar  = Db + 6*HBE - (size_t)3*NN*NN;

    k_prep_adj<<<dim3(32,32,3), dim3(32,8), 0, stream>>>(a0, a1, a2, At, Ar);
    k_prep_x2 <<<dim3(NN/64, NB*NC), 256, 0, stream>>>(x, Zt);
    k_bgemm<2><<<dim3(NJ/128, NN/128, 3), 256, 0, stream>>>(At, Ar, At, Zt, Db);
    k_bgemm<3><<<dim3(NJ/128, NN/128, 3), 256, 0, stream>>>(At, Ar, At, Zt, Db);
    k_mix7<<<dim3(NN/128, NB*NT), 256, 0, stream>>>(Zt, Db, W, bias);
    k_out2<<<dim3(NN/256, NB*NO), 256, 0, stream>>>(Zt, y);
  }
}

// Round 19
// 221.861 us; speedup vs baseline: 1.0329x; 1.0329x over previous
//
#include <hip/hip_runtime.h>
#include <stdint.h>

#define NB 32      // batch
#define NC 32      // in channels
#define NN 1024    // nodes
#define NT 12      // time
#define NJ (NB*NC*NT)  // 12288
#define NO 32      // out channels
#define TIN 224    // (2*3+1)*32
#define HBE ((size_t)NJ*NN)   // elements per [j][n] buffer

typedef __attribute__((ext_vector_type(8))) __bf16 bf16x8;
typedef __attribute__((ext_vector_type(4))) float f32x4;
typedef unsigned short u16;
typedef unsigned int u32;

__device__ __forceinline__ u16 f2bf(float f){
  u32 u = __float_as_uint(f);
  u32 r = (u + 0x7FFFu + ((u >> 16) & 1u)) >> 16;   // RNE
  return (u16)r;
}
__device__ __forceinline__ float bf2f(u16 h){
  return __uint_as_float(((u32)h) << 16);
}
__device__ __forceinline__ float bflo(u32 v){ return __uint_as_float(v << 16); }
__device__ __forceinline__ float bfhi(u32 v){ return __uint_as_float(v & 0xFFFF0000u); }

typedef const __attribute__((address_space(1))) u32* gp_t;
typedef __attribute__((address_space(3))) u32* lp_t;
__device__ __forceinline__ void gll16(const void* g, void* l){
  __builtin_amdgcn_global_load_lds((gp_t)g, (lp_t)l, 16, 0, 0);
}

// ---------- prep adj: At[z][m][n] = bf16(adj_z[n][m]) ; Ar[z][n][m] = bf16(adj_z[n][m]) ----------
__global__ __launch_bounds__(256) void k_prep_adj(const float* __restrict__ a0,
      const float* __restrict__ a1, const float* __restrict__ a2,
      u16* __restrict__ At, u16* __restrict__ Ar){
  __shared__ float tile[32][33];
  const float* A = (blockIdx.z==0) ? a0 : (blockIdx.z==1 ? a1 : a2);
  int n0 = blockIdx.x*32, m0 = blockIdx.y*32;
  int tx = threadIdx.x, ty = threadIdx.y;  // block (32,8)
  u16* dstR = Ar + (size_t)blockIdx.z*NN*NN;
  #pragma unroll
  for (int r=0;r<4;r++){
    float v = A[(size_t)(n0 + ty + 8*r)*NN + m0 + tx];
    tile[ty + 8*r][tx] = v;
    dstR[(size_t)(n0 + ty + 8*r)*NN + m0 + tx] = f2bf(v);
  }
  __syncthreads();
  u16* dst = At + (size_t)blockIdx.z*NN*NN;
  #pragma unroll
  for (int r=0;r<4;r++)
    dst[(size_t)(m0 + ty + 8*r)*NN + n0 + tx] = f2bf(tile[tx][ty + 8*r]);
}

// ---------- prep x (fallback layout): Zt[j][n] = bf16(x[p,n,t]) ----------
__global__ __launch_bounds__(256) void k_prep_x2(const float* __restrict__ x, u16* __restrict__ Zt){
  __shared__ float tl[64][13];
  int p = blockIdx.y, n0 = blockIdx.x*64;
  const float* xp = x + (size_t)p*NN*NT + (size_t)n0*NT;
  int tid = threadIdx.x;
  #pragma unroll
  for (int k=0;k<3;k++){
    int e = tid + k*256;
    float v = xp[e];
    tl[e/12][e%12] = v;
  }
  __syncthreads();
  #pragma unroll
  for (int k=0;k<3;k++){
    int e = tid + k*256;
    int t = e >> 6, nn = e & 63;
    Zt[((size_t)p*NT + t)*NN + n0 + nn] = f2bf(tl[nn][t]);
  }
}

// ---------- fused prep_x + premix (R16-proven): per (b, 64n) block, all 12 t ----------
__global__ __launch_bounds__(256) void k_pmix2(const float* __restrict__ x,
    const float* __restrict__ W, const float* __restrict__ bias,
    u16* __restrict__ U, u16* __restrict__ Base){
  __shared__ __align__(16) u16 X[12*64*40];   // [t][nl][c pitch 40] = 60 KB
  int tid = threadIdx.x;
  int n0 = blockIdx.x*64, b = blockIdx.y;

  #pragma unroll
  for (int k=0;k<24;k++){
    int idx = tid + k*256;            // 6144 float4 per block
    int c = idx / 192, f = idx - c*192;
    float4 v = *reinterpret_cast<const float4*>(
        x + ((size_t)(b*NC + c)*NN + n0)*NT + f*4);
    #pragma unroll
    for (int j=0;j<4;j++){
      int e = f*4 + j;
      int nl = e / 12, tt = e - nl*12;
      float fv = (j==0)?v.x:(j==1)?v.y:(j==2)?v.z:v.w;
      X[(tt*64 + nl)*40 + c] = f2bf(fv);
    }
  }

  int lane = tid & 63, w = tid >> 6;
  int lrow = lane & 15, kgrp = lane >> 4;

  bf16x8 af[7][2];
  #pragma unroll
  for (int g=0; g<7; g++){
    #pragma unroll
    for (int ot=0; ot<2; ot++){
      const float* wr = W + (size_t)(ot*16 + lrow)*TIN + g*32 + kgrp*8;
      float4 wa = *reinterpret_cast<const float4*>(wr);
      float4 wb = *reinterpret_cast<const float4*>(wr + 4);
      u32 tmp[4];
      tmp[0] = (u32)f2bf(wa.x) | ((u32)f2bf(wa.y) << 16);
      tmp[1] = (u32)f2bf(wa.z) | ((u32)f2bf(wa.w) << 16);
      tmp[2] = (u32)f2bf(wb.x) | ((u32)f2bf(wb.y) << 16);
      tmp[3] = (u32)f2bf(wb.z) | ((u32)f2bf(wb.w) << 16);
      af[g][ot] = *reinterpret_cast<bf16x8*>(tmp);
    }
  }
  float4 bias4[2];
  #pragma unroll
  for (int ot=0; ot<2; ot++)
    bias4[ot] = *reinterpret_cast<const float4*>(bias + ot*16 + kgrp*4);

  __syncthreads();

  #pragma unroll 1
  for (int t=0; t<12; ++t){
    bf16x8 bfr = *reinterpret_cast<const bf16x8*>(
        &X[((t*64) + w*16 + lrow)*40 + kgrp*8]);
    #pragma unroll
    for (int g=0; g<7; g++){
      u16* dstb = (g==0) ? Base : (U + (size_t)(g-1)*HBE);
      #pragma unroll
      for (int ot=0; ot<2; ot++){
        f32x4 acc = (f32x4){0.f,0.f,0.f,0.f};
        acc = __builtin_amdgcn_mfma_f32_16x16x32_bf16(af[g][ot], bfr, acc, 0, 0, 0);
        if (g==0){
          acc[0] += bias4[ot].x; acc[1] += bias4[ot].y;
          acc[2] += bias4[ot].z; acc[3] += bias4[ot].w;
        }
        int o = ot*16 + kgrp*4;
        size_t rb = ((size_t)(b*NO + o)*NT + t)*NN + n0 + w*16 + lrow;
        dstb[rb]                    = f2bf(acc[0]);
        dstb[rb + (size_t)NT*NN]    = f2bf(acc[1]);
        dstb[rb + (size_t)2*NT*NN]  = f2bf(acc[2]);
        dstb[rb + (size_t)3*NT*NN]  = f2bf(acc[3]);
      }
    }
  }
}

// ---------- batched GEMM, 2-phase double-buffered, MODE 0 (At2) / 2 / 3 (fallback) ----------
#define BKK 64
template<int MODE>
__global__ __launch_bounds__(256) void k_bgemm(
    const u16* __restrict__ At, const u16* __restrict__ Ar,
    u16* __restrict__ At2, const u16* __restrict__ Zt,
    u16* __restrict__ Db){
  __shared__ __align__(16) u16 As[2][128*BKK];
  __shared__ __align__(16) u16 Bs[2][128*BKK];
  int tid = threadIdx.x;
  int w = tid >> 6, lane = tid & 63;
  int z = blockIdx.z;
  int m0 = blockIdx.y * 128, j0 = blockIdx.x * 128;
  int wr = w >> 1, wc = w & 1;
  int lrow = lane & 15, kgrp = lane >> 4;
  int lr8 = lane >> 3, lc8 = lane & 7;

  const u16* Amat; const u16* Bmat; u16* Out;
  if (MODE==0){
    Amat = Ar + (size_t)z*NN*NN; Bmat = At + (size_t)z*NN*NN; Out = At2 + (size_t)z*NN*NN;
  } else if (MODE==2){
    Amat = At + (size_t)z*NN*NN; Bmat = Zt; Out = Db + (size_t)(2*z)*HBE;
  } else {
    Amat = At + (size_t)z*NN*NN; Bmat = Db + (size_t)(2*z)*HBE; Out = Db + (size_t)(2*z+1)*HBE;
  }

  f32x4 acc[4][4];
  #pragma unroll
  for (int i=0;i<4;i++)
    #pragma unroll
    for (int jj=0;jj<4;jj++)
      acc[i][jj] = (f32x4){0.f,0.f,0.f,0.f};

  const u16* Abase = Amat + (size_t)m0*1024;
  const u16* Bbase = Bmat + (size_t)j0*1024;

  auto stage = [&](int kt, int d){
    int k0 = kt*BKK;
    #pragma unroll
    for (int i=0;i<4;i++){
      int q = w*4 + i;
      int row = q*8 + lr8;
      gll16(Abase + (size_t)row*1024 + k0 + lc8*8, (u16*)&As[d][0] + q*512);
      gll16(Bbase + (size_t)row*1024 + k0 + lc8*8, (u16*)&Bs[d][0] + q*512);
    }
  };
  auto compute = [&](int d){
    #pragma unroll
    for (int kk=0; kk<2; ++kk){
      bf16x8 af[4], bfr[4];
      #pragma unroll
      for (int mi=0;mi<4;mi++)
        af[mi] = *reinterpret_cast<const bf16x8*>(&As[d][(wr*64+mi*16+lrow)*BKK + kk*32 + kgrp*8]);
      #pragma unroll
      for (int ji=0;ji<4;ji++)
        bfr[ji] = *reinterpret_cast<const bf16x8*>(&Bs[d][(wc*64+ji*16+lrow)*BKK + kk*32 + kgrp*8]);
      #pragma unroll
      for (int mi=0;mi<4;mi++)
        #pragma unroll
        for (int ji=0;ji<4;ji++)
          acc[mi][ji] = __builtin_amdgcn_mfma_f32_16x16x32_bf16(af[mi], bfr[ji], acc[mi][ji], 0, 0, 0);
    }
  };

  stage(0, 0);
  #pragma unroll 1
  for (int kt2=0; kt2<8; ++kt2){
    stage(2*kt2+1, 1);
    asm volatile("s_waitcnt vmcnt(8)" ::: "memory");
    __builtin_amdgcn_s_barrier();
    compute(0);
    __builtin_amdgcn_s_barrier();
    if (kt2 < 7){
      stage(2*kt2+2, 0);
      asm volatile("s_waitcnt vmcnt(8)" ::: "memory");
    } else {
      asm volatile("s_waitcnt vmcnt(0)" ::: "memory");
    }
    __builtin_amdgcn_s_barrier();
    compute(1);
    __builtin_amdgcn_s_barrier();
  }

  #pragma unroll
  for (int mi=0;mi<4;mi++){
    #pragma unroll
    for (int ji=0;ji<4;ji++){
      int jg = j0 + wc*64 + ji*16 + lrow;
      int mg = m0 + wr*64 + mi*16 + kgrp*4;
      ushort4 st;
      st.x = f2bf(acc[mi][ji][0]);
      st.y = f2bf(acc[mi][ji][1]);
      st.z = f2bf(acc[mi][ji][2]);
      st.w = f2bf(acc[mi][ji][3]);
      *reinterpret_cast<ushort4*>(&Out[(size_t)jg*NN + mg]) = st;
    }
  }
}

// ---------- fused 6-term GEMM (R11-proven main loop) + fused f32 transpose epilogue ----------
__global__ __launch_bounds__(512) void k_gemm6p(
    const u16* __restrict__ At, const u16* __restrict__ At2,
    const u16* __restrict__ U, const u16* __restrict__ Base,
    float* __restrict__ y){
  __shared__ __align__(16) u16 lds[2][28672];   // per buf: A 256x64 @0, B 192x64 @16384
  const int tid = threadIdx.x;
  const int w = tid >> 6, lane = tid & 63;
  const int lrow = lane & 15, kgrp = lane >> 4;
  const int wm = w & 3, wj = w >> 2;
  const int swz = (lrow & 7) << 3;           // read-side XOR (u16 units, 16B slots)

  const int orig = blockIdx.x;
  const int wg = (orig & 7)*32 + (orig >> 3);  // bijective XCD remap (256 = 8*32)
  const int m0 = (wg >> 6) * 256;
  const int j0 = (wg & 63) * 192;

  const int srow = lane >> 3;
  const int skoff = ((lane & 7) << 3) ^ ((srow & 7) << 3);   // inverse-swizzled k-off
  size_t rowoff[7]; int ldsoff[7]; bool isA[7];
  #pragma unroll
  for (int i=0;i<7;i++){
    int c = w*7 + i;
    if (c < 32){
      int row = c*8 + srow;
      isA[i] = true;  rowoff[i] = (size_t)(m0 + row)*1024 + skoff;  ldsoff[i] = c*512;
    } else {
      int cb = c - 32;
      int row = cb*8 + srow;
      isA[i] = false; rowoff[i] = (size_t)(j0 + row)*1024 + skoff;  ldsoff[i] = 16384 + cb*512;
    }
  }

  #define STAGE(t, i) {                                                        \
    int s_ = (t) >> 4;                                                         \
    int k0_ = ((t) & 15) << 6;                                                 \
    const u16* Ab_ = ((s_ & 1) ? At2 : At) + (size_t)(s_ >> 1)*NN*NN;          \
    const u16* src_ = (isA[i] ? Ab_ : (U + (size_t)s_*HBE)) + rowoff[i] + k0_; \
    gll16(src_, &lds[(t) & 1][ldsoff[i]]); }

  f32x4 acc[4][6];
  #pragma unroll
  for (int mi=0;mi<4;mi++)
    #pragma unroll
    for (int ji=0;ji<6;ji++)
      acc[mi][ji] = (f32x4){0.f,0.f,0.f,0.f};

  #pragma unroll
  for (int i=0;i<7;i++) STAGE(0, i)

  #pragma unroll 1
  for (int t=0; t<96; ++t){
    const int d = t & 1;
    if (t < 95){
      STAGE(t+1, 0) STAGE(t+1, 1)
      asm volatile("s_waitcnt vmcnt(2)" ::: "memory");
    } else {
      asm volatile("s_waitcnt vmcnt(0)" ::: "memory");
    }
    __builtin_amdgcn_s_barrier();
    __builtin_amdgcn_sched_barrier(0);

    bf16x8 bf[6][2];
    #pragma unroll
    for (int p=0;p<4;p++){
      if (t < 95){
        if (p==0){ STAGE(t+1, 2) STAGE(t+1, 3) }
        else if (p==1){ STAGE(t+1, 4) STAGE(t+1, 5) }
        else if (p==2){ STAGE(t+1, 6) }
      }
      if (p==0){
        #pragma unroll
        for (int ji=0;ji<6;ji++){
          int row = wj*96 + ji*16 + lrow;
          #pragma unroll
          for (int kk=0;kk<2;kk++)
            bf[ji][kk] = *reinterpret_cast<const bf16x8*>(
              &lds[d][16384 + row*64 + ((kk*32 + kgrp*8) ^ swz)]);
        }
      }
      bf16x8 af0, af1;
      {
        int row = wm*64 + p*16 + lrow;
        af0 = *reinterpret_cast<const bf16x8*>(&lds[d][row*64 + ((kgrp*8) ^ swz)]);
        af1 = *reinterpret_cast<const bf16x8*>(&lds[d][row*64 + ((32 + kgrp*8) ^ swz)]);
      }
      __builtin_amdgcn_s_setprio(1);
      #pragma unroll
      for (int ji=0;ji<6;ji++){
        acc[p][ji] = __builtin_amdgcn_mfma_f32_16x16x32_bf16(af0, bf[ji][0], acc[p][ji], 0, 0, 0);
        acc[p][ji] = __builtin_amdgcn_mfma_f32_16x16x32_bf16(af1, bf[ji][1], acc[p][ji], 0, 0, 0);
      }
      __builtin_amdgcn_s_setprio(0);
    }
    __builtin_amdgcn_s_barrier();   // all waves done reading buf d before t+2 stages hit it
  }
  #undef STAGE

  // ---- fused transpose epilogue: y[bo][n][t] f32, via LDS, fully coalesced ----
  float* ldsf = (float*)&lds[0][0];           // 96 KB of the 112 KB staging LDS
  const int bo0 = j0 / NT;                    // j0 % 12 == 0
  #pragma unroll 1
  for (int r=0; r<2; ++r){
    if (r) __syncthreads();                   // round-0 readers done before round-1 writers
    if (wj == r){
      #pragma unroll
      for (int ji=0;ji<6;ji++){
        int jl = ji*16 + lrow;                // 0..95 within this wj half
        int bo8 = jl / NT, tt = jl - bo8*NT;  // bo8 in 0..7
        int jg = j0 + r*96 + jl;
        #pragma unroll
        for (int mi=0;mi<4;mi++){
          int nl = wm*64 + mi*16 + kgrp*4;
          const ushort4 bv = *reinterpret_cast<const ushort4*>(&Base[(size_t)jg*NN + m0 + nl]);
          float* p = ldsf + bo8*3072 + nl*NT + tt;
          p[0]  = acc[mi][ji][0] + bf2f(bv.x);
          p[12] = acc[mi][ji][1] + bf2f(bv.y);
          p[24] = acc[mi][ji][2] + bf2f(bv.z);
          p[36] = acc[mi][ji][3] + bf2f(bv.w);
        }
      }
    }
    __syncthreads();                          // writers done before readers
    #pragma unroll
    for (int q=0;q<12;q++){
      int idx = tid + q*512;                  // 6144 float4 per round
      int bo8 = idx / 768, off = (idx - bo8*768)*4;
      *reinterpret_cast<float4*>(y + ((size_t)(bo0 + r*8 + bo8))*(NN*NT) + (size_t)m0*NT + off)
        = *reinterpret_cast<const float4*>(ldsf + bo8*3072 + off);
    }
  }
}

// ---------- final channel mix (fallback path only) ----------
__global__ __launch_bounds__(256) void k_mix7(u16* zt_y,
    const u16* __restrict__ Db, const float* __restrict__ W,
    const float* __restrict__ bias){
  __shared__ u32 X[112][64];   // 28 KB
  int tid = threadIdx.x;
  int n0 = blockIdx.x*128;
  int bt = blockIdx.y;
  int b = bt / NT, t = bt - b*NT;
  int lane = tid & 63;
  int og = __builtin_amdgcn_readfirstlane(tid >> 6);

  float a0[8], a1[8];
  #pragma unroll
  for (int oo=0;oo<8;oo++){ float bv = bias[og*8+oo]; a0[oo]=bv; a1[oo]=bv; }

  #pragma unroll 1
  for (int chunk=0; chunk<2; ++chunk){
    if (chunk) __syncthreads();
    #pragma unroll
    for (int k=0;k<28;k++){
      int i = tid + k*256;
      int rl = i >> 6, col = i & 63;
      int r = chunk*112 + rl;
      int s = r >> 5, c = r & 31;
      const u16* src = (s==0) ? zt_y : (Db + (size_t)(s-1)*HBE);
      X[rl][col] = *reinterpret_cast<const u32*>(src + ((size_t)(b*NC + c)*NT + t)*NN + n0 + 2*col);
    }
    __syncthreads();
    #pragma unroll
    for (int cc=0; cc<112; ++cc){
      u32 xp = X[cc][lane];
      float xl = bflo(xp), xh = bfhi(xp);
      #pragma unroll
      for (int oo=0;oo<8;oo++){
        float w = W[(size_t)(og*8+oo)*TIN + chunk*112 + cc];
        a0[oo] += w*xl; a1[oo] += w*xh;
      }
    }
  }

  #pragma unroll
  for (int oo=0;oo<8;oo++){
    u32 pk = (u32)f2bf(a0[oo]) | ((u32)f2bf(a1[oo]) << 16);
    *reinterpret_cast<u32*>(zt_y + ((size_t)(b*NO + og*8+oo)*NT + t)*NN + n0 + 2*lane) = pk;
  }
}

// ---------- final transpose (fallback path) ----------
__global__ __launch_bounds__(256) void k_out2(const u16* __restrict__ Yb,
                                              float* __restrict__ y){
  __shared__ float tl[256][13];
  int n0 = blockIdx.x*256;
  int bo = blockIdx.y;
  int tid = threadIdx.x;
  #pragma unroll
  for (int k=0;k<12;k++)
    tl[tid][k] = bf2f(Yb[((size_t)bo*NT + k)*NN + n0 + tid]);
  __syncthreads();
  float* yp = y + ((size_t)bo*NN + n0)*NT;
  #pragma unroll
  for (int k=0;k<12;k++){
    int i = k*256 + tid;
    yp[i] = tl[i/12][i%12];
  }
}

extern "C" void kernel_launch(void* const* d_in, const int* in_sizes, int n_in,
                              void* d_out, int out_size, void* d_ws, size_t ws_size,
                              hipStream_t stream){
  const float* x    = (const float*)d_in[0];
  const float* a0   = (const float*)d_in[1];
  const float* a1   = (const float*)d_in[2];
  const float* a2   = (const float*)d_in[3];
  const float* W    = (const float*)d_in[4];
  const float* bias = (const float*)d_in[5];
  float* y = (float*)d_out;
  (void)in_sizes; (void)n_in; (void)out_size;

  const size_t atB = (size_t)3*NN*NN*2;     // 6.29 MB
  const size_t ztB = HBE*2;                 // 25.17 MB
  const size_t need_fused = 2*atB + 8*ztB;  // 213.9 MB (R9-R18 verified available)

  if (ws_size >= need_fused){
    // R16-proven serialized flow + R18's dedicated Ar slot (no aliasing).
    char* ws = (char*)d_ws;
    u16* At   = (u16*)ws;  ws += atB;
    u16* At2  = (u16*)ws;  ws += atB;
    u16* Ar   = (u16*)ws;  ws += ztB;        // own slot (former Zc)
    u16* U    = (u16*)ws;  ws += 6*ztB;
    u16* Base = (u16*)ws;  ws += ztB;

    k_prep_adj<<<dim3(32,32,3), dim3(32,8), 0, stream>>>(a0, a1, a2, At, Ar);
    k_bgemm<0><<<dim3(NN/128, NN/128, 3), 256, 0, stream>>>(At, Ar, At2, nullptr, U);
    k_pmix2<<<dim3(NN/64, NB), 256, 0, stream>>>(x, W, bias, U, Base);
    k_gemm6p<<<256, 512, 0, stream>>>(At, At2, U, Base, y);         // writes y directly
  } else {
    // fallback: two dependent batched GEMM dispatches + late mix
    char* ws = (char*)d_ws;
    u16* At  = (u16*)ws;  ws += atB;
    u16* Zt  = (u16*)ws;  ws += ztB;
    u16* Db  = (u16*)ws;  ws += 6*ztB;
    u16* Ar  = Db + 6*HBE - (size_t)3*NN*NN;

    k_prep_adj<<<dim3(32,32,3), dim3(32,8), 0, stream>>>(a0, a1, a2, At, Ar);
    k_prep_x2 <<<dim3(NN/64, NB*NC), 256, 0, stream>>>(x, Zt);
    k_bgemm<2><<<dim3(NJ/128, NN/128, 3), 256, 0, stream>>>(At, Ar, At, Zt, Db);
    k_bgemm<3><<<dim3(NJ/128, NN/128, 3), 256, 0, stream>>>(At, Ar, At, Zt, Db);
    k_mix7<<<dim3(NN/128, NB*NT), 256, 0, stream>>>(Zt, Db, W, bias);
    k_out2<<<dim3(NN/256, NB*NO), 256, 0, stream>>>(Zt, y);
  }
}

// Round 20
// 216.180 us; speedup vs baseline: 1.0601x; 1.0263x over previous
//
#include <hip/hip_runtime.h>
#include <stdint.h>

#define NB 32      // batch
#define NC 32      // in channels
#define NN 1024    // nodes
#define NT 12      // time
#define NJ (NB*NC*NT)  // 12288
#define NO 32      // out channels
#define TIN 224    // (2*3+1)*32
#define HBE ((size_t)NJ*NN)   // elements per [j][n] buffer

typedef __attribute__((ext_vector_type(8))) __bf16 bf16x8;
typedef __attribute__((ext_vector_type(4))) float f32x4;
typedef unsigned short u16;
typedef unsigned int u32;

__device__ __forceinline__ u16 f2bf(float f){
  u32 u = __float_as_uint(f);
  u32 r = (u + 0x7FFFu + ((u >> 16) & 1u)) >> 16;   // RNE
  return (u16)r;
}
__device__ __forceinline__ float bf2f(u16 h){
  return __uint_as_float(((u32)h) << 16);
}
__device__ __forceinline__ float bflo(u32 v){ return __uint_as_float(v << 16); }
__device__ __forceinline__ float bfhi(u32 v){ return __uint_as_float(v & 0xFFFF0000u); }

typedef const __attribute__((address_space(1))) u32* gp_t;
typedef __attribute__((address_space(3))) u32* lp_t;
__device__ __forceinline__ void gll16(const void* g, void* l){
  __builtin_amdgcn_global_load_lds((gp_t)g, (lp_t)l, 16, 0, 0);
}

// ---------- prep adj: At[z][m][n] = bf16(adj_z[n][m]) ; Ar[z][n][m] = bf16(adj_z[n][m]) ----------
__global__ __launch_bounds__(256) void k_prep_adj(const float* __restrict__ a0,
      const float* __restrict__ a1, const float* __restrict__ a2,
      u16* __restrict__ At, u16* __restrict__ Ar){
  __shared__ float tile[32][33];
  const float* A = (blockIdx.z==0) ? a0 : (blockIdx.z==1 ? a1 : a2);
  int n0 = blockIdx.x*32, m0 = blockIdx.y*32;
  int tx = threadIdx.x, ty = threadIdx.y;  // block (32,8)
  u16* dstR = Ar + (size_t)blockIdx.z*NN*NN;
  #pragma unroll
  for (int r=0;r<4;r++){
    float v = A[(size_t)(n0 + ty + 8*r)*NN + m0 + tx];
    tile[ty + 8*r][tx] = v;
    dstR[(size_t)(n0 + ty + 8*r)*NN + m0 + tx] = f2bf(v);
  }
  __syncthreads();
  u16* dst = At + (size_t)blockIdx.z*NN*NN;
  #pragma unroll
  for (int r=0;r<4;r++)
    dst[(size_t)(m0 + ty + 8*r)*NN + n0 + tx] = f2bf(tile[tx][ty + 8*r]);
}

// ---------- prep x (fallback layout): Zt[j][n] = bf16(x[p,n,t]) ----------
__global__ __launch_bounds__(256) void k_prep_x2(const float* __restrict__ x, u16* __restrict__ Zt){
  __shared__ float tl[64][13];
  int p = blockIdx.y, n0 = blockIdx.x*64;
  const float* xp = x + (size_t)p*NN*NT + (size_t)n0*NT;
  int tid = threadIdx.x;
  #pragma unroll
  for (int k=0;k<3;k++){
    int e = tid + k*256;
    float v = xp[e];
    tl[e/12][e%12] = v;
  }
  __syncthreads();
  #pragma unroll
  for (int k=0;k<3;k++){
    int e = tid + k*256;
    int t = e >> 6, nn = e & 63;
    Zt[((size_t)p*NT + t)*NN + n0 + nn] = f2bf(tl[nn][t]);
  }
}

// ---------- fused prep_x + premix (R16-proven): per (b, 64n) block, all 12 t ----------
__global__ __launch_bounds__(256) void k_pmix2(const float* __restrict__ x,
    const float* __restrict__ W, const float* __restrict__ bias,
    u16* __restrict__ U, u16* __restrict__ Base){
  __shared__ __align__(16) u16 X[12*64*40];   // [t][nl][c pitch 40] = 60 KB
  int tid = threadIdx.x;
  int n0 = blockIdx.x*64, b = blockIdx.y;

  #pragma unroll
  for (int k=0;k<24;k++){
    int idx = tid + k*256;            // 6144 float4 per block
    int c = idx / 192, f = idx - c*192;
    float4 v = *reinterpret_cast<const float4*>(
        x + ((size_t)(b*NC + c)*NN + n0)*NT + f*4);
    #pragma unroll
    for (int j=0;j<4;j++){
      int e = f*4 + j;
      int nl = e / 12, tt = e - nl*12;
      float fv = (j==0)?v.x:(j==1)?v.y:(j==2)?v.z:v.w;
      X[(tt*64 + nl)*40 + c] = f2bf(fv);
    }
  }

  int lane = tid & 63, w = tid >> 6;
  int lrow = lane & 15, kgrp = lane >> 4;

  bf16x8 af[7][2];
  #pragma unroll
  for (int g=0; g<7; g++){
    #pragma unroll
    for (int ot=0; ot<2; ot++){
      const float* wr = W + (size_t)(ot*16 + lrow)*TIN + g*32 + kgrp*8;
      float4 wa = *reinterpret_cast<const float4*>(wr);
      float4 wb = *reinterpret_cast<const float4*>(wr + 4);
      u32 tmp[4];
      tmp[0] = (u32)f2bf(wa.x) | ((u32)f2bf(wa.y) << 16);
      tmp[1] = (u32)f2bf(wa.z) | ((u32)f2bf(wa.w) << 16);
      tmp[2] = (u32)f2bf(wb.x) | ((u32)f2bf(wb.y) << 16);
      tmp[3] = (u32)f2bf(wb.z) | ((u32)f2bf(wb.w) << 16);
      af[g][ot] = *reinterpret_cast<bf16x8*>(tmp);
    }
  }
  float4 bias4[2];
  #pragma unroll
  for (int ot=0; ot<2; ot++)
    bias4[ot] = *reinterpret_cast<const float4*>(bias + ot*16 + kgrp*4);

  __syncthreads();

  #pragma unroll 1
  for (int t=0; t<12; ++t){
    bf16x8 bfr = *reinterpret_cast<const bf16x8*>(
        &X[((t*64) + w*16 + lrow)*40 + kgrp*8]);
    #pragma unroll
    for (int g=0; g<7; g++){
      u16* dstb = (g==0) ? Base : (U + (size_t)(g-1)*HBE);
      #pragma unroll
      for (int ot=0; ot<2; ot++){
        f32x4 acc = (f32x4){0.f,0.f,0.f,0.f};
        acc = __builtin_amdgcn_mfma_f32_16x16x32_bf16(af[g][ot], bfr, acc, 0, 0, 0);
        if (g==0){
          acc[0] += bias4[ot].x; acc[1] += bias4[ot].y;
          acc[2] += bias4[ot].z; acc[3] += bias4[ot].w;
        }
        int o = ot*16 + kgrp*4;
        size_t rb = ((size_t)(b*NO + o)*NT + t)*NN + n0 + w*16 + lrow;
        dstb[rb]                    = f2bf(acc[0]);
        dstb[rb + (size_t)NT*NN]    = f2bf(acc[1]);
        dstb[rb + (size_t)2*NT*NN]  = f2bf(acc[2]);
        dstb[rb + (size_t)3*NT*NN]  = f2bf(acc[3]);
      }
    }
  }
}

// ---------- batched GEMM, 2-phase double-buffered, MODE 0 (At2) / 2 / 3 (fallback) ----------
#define BKK 64
template<int MODE>
__global__ __launch_bounds__(256) void k_bgemm(
    const u16* __restrict__ At, const u16* __restrict__ Ar,
    u16* __restrict__ At2, const u16* __restrict__ Zt,
    u16* __restrict__ Db){
  __shared__ __align__(16) u16 As[2][128*BKK];
  __shared__ __align__(16) u16 Bs[2][128*BKK];
  int tid = threadIdx.x;
  int w = tid >> 6, lane = tid & 63;
  int z = blockIdx.z;
  int m0 = blockIdx.y * 128, j0 = blockIdx.x * 128;
  int wr = w >> 1, wc = w & 1;
  int lrow = lane & 15, kgrp = lane >> 4;
  int lr8 = lane >> 3, lc8 = lane & 7;

  const u16* Amat; const u16* Bmat; u16* Out;
  if (MODE==0){
    Amat = Ar + (size_t)z*NN*NN; Bmat = At + (size_t)z*NN*NN; Out = At2 + (size_t)z*NN*NN;
  } else if (MODE==2){
    Amat = At + (size_t)z*NN*NN; Bmat = Zt; Out = Db + (size_t)(2*z)*HBE;
  } else {
    Amat = At + (size_t)z*NN*NN; Bmat = Db + (size_t)(2*z)*HBE; Out = Db + (size_t)(2*z+1)*HBE;
  }

  f32x4 acc[4][4];
  #pragma unroll
  for (int i=0;i<4;i++)
    #pragma unroll
    for (int jj=0;jj<4;jj++)
      acc[i][jj] = (f32x4){0.f,0.f,0.f,0.f};

  const u16* Abase = Amat + (size_t)m0*1024;
  const u16* Bbase = Bmat + (size_t)j0*1024;

  auto stage = [&](int kt, int d){
    int k0 = kt*BKK;
    #pragma unroll
    for (int i=0;i<4;i++){
      int q = w*4 + i;
      int row = q*8 + lr8;
      gll16(Abase + (size_t)row*1024 + k0 + lc8*8, (u16*)&As[d][0] + q*512);
      gll16(Bbase + (size_t)row*1024 + k0 + lc8*8, (u16*)&Bs[d][0] + q*512);
    }
  };
  auto compute = [&](int d){
    #pragma unroll
    for (int kk=0; kk<2; ++kk){
      bf16x8 af[4], bfr[4];
      #pragma unroll
      for (int mi=0;mi<4;mi++)
        af[mi] = *reinterpret_cast<const bf16x8*>(&As[d][(wr*64+mi*16+lrow)*BKK + kk*32 + kgrp*8]);
      #pragma unroll
      for (int ji=0;ji<4;ji++)
        bfr[ji] = *reinterpret_cast<const bf16x8*>(&Bs[d][(wc*64+ji*16+lrow)*BKK + kk*32 + kgrp*8]);
      #pragma unroll
      for (int mi=0;mi<4;mi++)
        #pragma unroll
        for (int ji=0;ji<4;ji++)
          acc[mi][ji] = __builtin_amdgcn_mfma_f32_16x16x32_bf16(af[mi], bfr[ji], acc[mi][ji], 0, 0, 0);
    }
  };

  stage(0, 0);
  #pragma unroll 1
  for (int kt2=0; kt2<8; ++kt2){
    stage(2*kt2+1, 1);
    asm volatile("s_waitcnt vmcnt(8)" ::: "memory");
    __builtin_amdgcn_s_barrier();
    compute(0);
    __builtin_amdgcn_s_barrier();
    if (kt2 < 7){
      stage(2*kt2+2, 0);
      asm volatile("s_waitcnt vmcnt(8)" ::: "memory");
    } else {
      asm volatile("s_waitcnt vmcnt(0)" ::: "memory");
    }
    __builtin_amdgcn_s_barrier();
    compute(1);
    __builtin_amdgcn_s_barrier();
  }

  #pragma unroll
  for (int mi=0;mi<4;mi++){
    #pragma unroll
    for (int ji=0;ji<4;ji++){
      int jg = j0 + wc*64 + ji*16 + lrow;
      int mg = m0 + wr*64 + mi*16 + kgrp*4;
      ushort4 st;
      st.x = f2bf(acc[mi][ji][0]);
      st.y = f2bf(acc[mi][ji][1]);
      st.z = f2bf(acc[mi][ji][2]);
      st.w = f2bf(acc[mi][ji][3]);
      *reinterpret_cast<ushort4*>(&Out[(size_t)jg*NN + mg]) = st;
    }
  }
}

// ---------- fused 6-term GEMM (R11-proven main loop) + fused f32 transpose epilogue ----------
// R19 change (only): j-major XCD remap — the 4 same-j0 blocks (different m0)
// land on ONE XCD and run in lockstep, so U k-stripes L2-hit 3-of-4 instead of
// being fetched by 4 XCDs. Pure bijective index change; main loop untouched.
__global__ __launch_bounds__(512) void k_gemm6p(
    const u16* __restrict__ At, const u16* __restrict__ At2,
    const u16* __restrict__ U, const u16* __restrict__ Base,
    float* __restrict__ y){
  __shared__ __align__(16) u16 lds[2][28672];   // per buf: A 256x64 @0, B 192x64 @16384
  const int tid = threadIdx.x;
  const int w = tid >> 6, lane = tid & 63;
  const int lrow = lane & 15, kgrp = lane >> 4;
  const int wm = w & 3, wj = w >> 2;
  const int swz = (lrow & 7) << 3;           // read-side XOR (u16 units, 16B slots)

  const int orig = blockIdx.x;
  // j-major XCD remap: xcd = orig&7; each XCD owns j-panels {xcd, xcd+8, ..} and
  // all 4 m-tiles of each (slots 0..31). Bijective over 256 blocks.
  const int xcd = orig & 7, slot = orig >> 3;
  const int m0 = (slot >> 3) * 256;
  const int j0 = (xcd + 8*(slot & 7)) * 192;

  const int srow = lane >> 3;
  const int skoff = ((lane & 7) << 3) ^ ((srow & 7) << 3);   // inverse-swizzled k-off
  size_t rowoff[7]; int ldsoff[7]; bool isA[7];
  #pragma unroll
  for (int i=0;i<7;i++){
    int c = w*7 + i;
    if (c < 32){
      int row = c*8 + srow;
      isA[i] = true;  rowoff[i] = (size_t)(m0 + row)*1024 + skoff;  ldsoff[i] = c*512;
    } else {
      int cb = c - 32;
      int row = cb*8 + srow;
      isA[i] = false; rowoff[i] = (size_t)(j0 + row)*1024 + skoff;  ldsoff[i] = 16384 + cb*512;
    }
  }

  #define STAGE(t, i) {                                                        \
    int s_ = (t) >> 4;                                                         \
    int k0_ = ((t) & 15) << 6;                                                 \
    const u16* Ab_ = ((s_ & 1) ? At2 : At) + (size_t)(s_ >> 1)*NN*NN;          \
    const u16* src_ = (isA[i] ? Ab_ : (U + (size_t)s_*HBE)) + rowoff[i] + k0_; \
    gll16(src_, &lds[(t) & 1][ldsoff[i]]); }

  f32x4 acc[4][6];
  #pragma unroll
  for (int mi=0;mi<4;mi++)
    #pragma unroll
    for (int ji=0;ji<6;ji++)
      acc[mi][ji] = (f32x4){0.f,0.f,0.f,0.f};

  #pragma unroll
  for (int i=0;i<7;i++) STAGE(0, i)

  #pragma unroll 1
  for (int t=0; t<96; ++t){
    const int d = t & 1;
    if (t < 95){
      STAGE(t+1, 0) STAGE(t+1, 1)
      asm volatile("s_waitcnt vmcnt(2)" ::: "memory");
    } else {
      asm volatile("s_waitcnt vmcnt(0)" ::: "memory");
    }
    __builtin_amdgcn_s_barrier();
    __builtin_amdgcn_sched_barrier(0);

    bf16x8 bf[6][2];
    #pragma unroll
    for (int p=0;p<4;p++){
      if (t < 95){
        if (p==0){ STAGE(t+1, 2) STAGE(t+1, 3) }
        else if (p==1){ STAGE(t+1, 4) STAGE(t+1, 5) }
        else if (p==2){ STAGE(t+1, 6) }
      }
      if (p==0){
        #pragma unroll
        for (int ji=0;ji<6;ji++){
          int row = wj*96 + ji*16 + lrow;
          #pragma unroll
          for (int kk=0;kk<2;kk++)
            bf[ji][kk] = *reinterpret_cast<const bf16x8*>(
              &lds[d][16384 + row*64 + ((kk*32 + kgrp*8) ^ swz)]);
        }
      }
      bf16x8 af0, af1;
      {
        int row = wm*64 + p*16 + lrow;
        af0 = *reinterpret_cast<const bf16x8*>(&lds[d][row*64 + ((kgrp*8) ^ swz)]);
        af1 = *reinterpret_cast<const bf16x8*>(&lds[d][row*64 + ((32 + kgrp*8) ^ swz)]);
      }
      __builtin_amdgcn_s_setprio(1);
      #pragma unroll
      for (int ji=0;ji<6;ji++){
        acc[p][ji] = __builtin_amdgcn_mfma_f32_16x16x32_bf16(af0, bf[ji][0], acc[p][ji], 0, 0, 0);
        acc[p][ji] = __builtin_amdgcn_mfma_f32_16x16x32_bf16(af1, bf[ji][1], acc[p][ji], 0, 0, 0);
      }
      __builtin_amdgcn_s_setprio(0);
    }
    __builtin_amdgcn_s_barrier();   // all waves done reading buf d before t+2 stages hit it
  }
  #undef STAGE

  // ---- fused transpose epilogue: y[bo][n][t] f32, via LDS, fully coalesced ----
  float* ldsf = (float*)&lds[0][0];           // 96 KB of the 112 KB staging LDS
  const int bo0 = j0 / NT;                    // j0 % 12 == 0
  #pragma unroll 1
  for (int r=0; r<2; ++r){
    if (r) __syncthreads();                   // round-0 readers done before round-1 writers
    if (wj == r){
      #pragma unroll
      for (int ji=0;ji<6;ji++){
        int jl = ji*16 + lrow;                // 0..95 within this wj half
        int bo8 = jl / NT, tt = jl - bo8*NT;  // bo8 in 0..7
        int jg = j0 + r*96 + jl;
        #pragma unroll
        for (int mi=0;mi<4;mi++){
          int nl = wm*64 + mi*16 + kgrp*4;
          const ushort4 bv = *reinterpret_cast<const ushort4*>(&Base[(size_t)jg*NN + m0 + nl]);
          float* p = ldsf + bo8*3072 + nl*NT + tt;
          p[0]  = acc[mi][ji][0] + bf2f(bv.x);
          p[12] = acc[mi][ji][1] + bf2f(bv.y);
          p[24] = acc[mi][ji][2] + bf2f(bv.z);
          p[36] = acc[mi][ji][3] + bf2f(bv.w);
        }
      }
    }
    __syncthreads();                          // writers done before readers
    #pragma unroll
    for (int q=0;q<12;q++){
      int idx = tid + q*512;                  // 6144 float4 per round
      int bo8 = idx / 768, off = (idx - bo8*768)*4;
      *reinterpret_cast<float4*>(y + ((size_t)(bo0 + r*8 + bo8))*(NN*NT) + (size_t)m0*NT + off)
        = *reinterpret_cast<const float4*>(ldsf + bo8*3072 + off);
    }
  }
}

// ---------- final channel mix (fallback path only) ----------
__global__ __launch_bounds__(256) void k_mix7(u16* zt_y,
    const u16* __restrict__ Db, const float* __restrict__ W,
    const float* __restrict__ bias){
  __shared__ u32 X[112][64];   // 28 KB
  int tid = threadIdx.x;
  int n0 = blockIdx.x*128;
  int bt = blockIdx.y;
  int b = bt / NT, t = bt - b*NT;
  int lane = tid & 63;
  int og = __builtin_amdgcn_readfirstlane(tid >> 6);

  float a0[8], a1[8];
  #pragma unroll
  for (int oo=0;oo<8;oo++){ float bv = bias[og*8+oo]; a0[oo]=bv; a1[oo]=bv; }

  #pragma unroll 1
  for (int chunk=0; chunk<2; ++chunk){
    if (chunk) __syncthreads();
    #pragma unroll
    for (int k=0;k<28;k++){
      int i = tid + k*256;
      int rl = i >> 6, col = i & 63;
      int r = chunk*112 + rl;
      int s = r >> 5, c = r & 31;
      const u16* src = (s==0) ? zt_y : (Db + (size_t)(s-1)*HBE);
      X[rl][col] = *reinterpret_cast<const u32*>(src + ((size_t)(b*NC + c)*NT + t)*NN + n0 + 2*col);
    }
    __syncthreads();
    #pragma unroll
    for (int cc=0; cc<112; ++cc){
      u32 xp = X[cc][lane];
      float xl = bflo(xp), xh = bfhi(xp);
      #pragma unroll
      for (int oo=0;oo<8;oo++){
        float w = W[(size_t)(og*8+oo)*TIN + chunk*112 + cc];
        a0[oo] += w*xl; a1[oo] += w*xh;
      }
    }
  }

  #pragma unroll
  for (int oo=0;oo<8;oo++){
    u32 pk = (u32)f2bf(a0[oo]) | ((u32)f2bf(a1[oo]) << 16);
    *reinterpret_cast<u32*>(zt_y + ((size_t)(b*NO + og*8+oo)*NT + t)*NN + n0 + 2*lane) = pk;
  }
}

// ---------- final transpose (fallback path) ----------
__global__ __launch_bounds__(256) void k_out2(const u16* __restrict__ Yb,
                                              float* __restrict__ y){
  __shared__ float tl[256][13];
  int n0 = blockIdx.x*256;
  int bo = blockIdx.y;
  int tid = threadIdx.x;
  #pragma unroll
  for (int k=0;k<12;k++)
    tl[tid][k] = bf2f(Yb[((size_t)bo*NT + k)*NN + n0 + tid]);
  __syncthreads();
  float* yp = y + ((size_t)bo*NN + n0)*NT;
  #pragma unroll
  for (int k=0;k<12;k++){
    int i = k*256 + tid;
    yp[i] = tl[i/12][i%12];
  }
}

extern "C" void kernel_launch(void* const* d_in, const int* in_sizes, int n_in,
                              void* d_out, int out_size, void* d_ws, size_t ws_size,
                              hipStream_t stream){
  const float* x    = (const float*)d_in[0];
  const float* a0   = (const float*)d_in[1];
  const float* a1   = (const float*)d_in[2];
  const float* a2   = (const float*)d_in[3];
  const float* W    = (const float*)d_in[4];
  const float* bias = (const float*)d_in[5];
  float* y = (float*)d_out;
  (void)in_sizes; (void)n_in; (void)out_size;

  const size_t atB = (size_t)3*NN*NN*2;     // 6.29 MB
  const size_t ztB = HBE*2;                 // 25.17 MB
  const size_t need_fused = 2*atB + 8*ztB;  // 213.9 MB (R9-R19 verified available)

  if (ws_size >= need_fused){
    char* ws = (char*)d_ws;
    u16* At   = (u16*)ws;  ws += atB;
    u16* At2  = (u16*)ws;  ws += atB;
    u16* Ar   = (u16*)ws;  ws += ztB;        // own slot (no aliasing)
    u16* U    = (u16*)ws;  ws += 6*ztB;
    u16* Base = (u16*)ws;  ws += ztB;

    k_prep_adj<<<dim3(32,32,3), dim3(32,8), 0, stream>>>(a0, a1, a2, At, Ar);
    k_bgemm<0><<<dim3(NN/128, NN/128, 3), 256, 0, stream>>>(At, Ar, At2, nullptr, U);
    k_pmix2<<<dim3(NN/64, NB), 256, 0, stream>>>(x, W, bias, U, Base);
    k_gemm6p<<<256, 512, 0, stream>>>(At, At2, U, Base, y);         // writes y directly
  } else {
    // fallback: two dependent batched GEMM dispatches + late mix
    char* ws = (char*)d_ws;
    u16* At  = (u16*)ws;  ws += atB;
    u16* Zt  = (u16*)ws;  ws += ztB;
    u16* Db  = (u16*)ws;  ws += 6*ztB;
    u16* Ar  = Db + 6*HBE - (size_t)3*NN*NN;

    k_prep_adj<<<dim3(32,32,3), dim3(32,8), 0, stream>>>(a0, a1, a2, At, Ar);
    k_prep_x2 <<<dim3(NN/64, NB*NC), 256, 0, stream>>>(x, Zt);
    k_bgemm<2><<<dim3(NJ/128, NN/128, 3), 256, 0, stream>>>(At, Ar, At, Zt, Db);
    k_bgemm<3><<<dim3(NJ/128, NN/128, 3), 256, 0, stream>>>(At, Ar, At, Zt, Db);
    k_mix7<<<dim3(NN/128, NB*NT), 256, 0, stream>>>(Zt, Db, W, bias);
    k_out2<<<dim3(NN/256, NB*NO), 256, 0, stream>>>(Zt, y);
  }
}